// Round 7
// baseline (158.336 us; speedup 1.0000x reference)
//
#include <hip/hip_runtime.h>

#define CH 30
#define CELLS 49
#define ROW 1470           // 49*30 floats per batch row
#define NPAIR 735          // ROW/2 float2 pairs
#define ITS 12             // ceil(735/64) pairs per lane
#define RPW 2              // rows per wave (software-pipelined)
#define WPB 4              // waves per block (256 threads)

__device__ __forceinline__ float waveReduce(float v) {
    #pragma unroll
    for (int o = 32; o > 0; o >>= 1) v += __shfl_xor(v, o, 64);
    return v;
}

__device__ __forceinline__ unsigned long long waveOr64(unsigned long long m) {
    #pragma unroll
    for (int o = 32; o > 0; o >>= 1) m |= __shfl_xor(m, o, 64);
    return m;
}

// Per-wave row processing. boxS/clist are this wave's private LDS slices; the
// wave runs in lockstep and the compiler inserts lgkmcnt waits, so no barriers.
__device__ __forceinline__ void processRow(const float* __restrict__ P,
                                           const float* __restrict__ T,
                                           const float2* pv, const float2* tv,
                                           int lane, float4* boxS, int* clist,
                                           float& cls, float& objc, float& coord) {
    // ---- obj mask from in-register stream (conf ch4 = pair rem==2, .x) ----
    unsigned long long contrib = 0ull;
    #pragma unroll
    for (int it = 0; it < ITS; ++it) {
        const int j = lane + it * 64;
        const int cell = (j * 17477) >> 18;          // j/15 for j<=767
        const int rem = j - cell * 15;
        if (j < NPAIR && rem == 2 && tv[it].x > 0.f) contrib |= (1ull << cell);
    }
    const unsigned long long mask = waveOr64(contrib);
    const int nObj = __popcll(mask);
    const bool isObj = (lane < CELLS) && ((mask >> lane) & 1ull);
    if (isObj) clist[__popcll(mask & ((1ull << lane) - 1ull))] = lane;

    // ---- branch-free weighted consume of the stream ----
    #pragma unroll
    for (int it = 0; it < ITS; ++it) {
        const int j = lane + it * 64;
        const bool valid = j < NPAIR;
        const int cell = (j * 17477) >> 18;
        const int ch0 = 2 * (j - cell * 15);         // even channel of the pair
        const float wobj = (float)((mask >> cell) & 1ull);
        const float dx = pv[it].x - tv[it].x;
        const float dy = pv[it].y - tv[it].y;
        // class loss: channels 10..29, obj cells only
        cls += (valid && ch0 >= 10) ? wobj * (dx * dx + dy * dy) : 0.f;
        // noobj conf loss (x0.5 folded): ch4 (.x of pair rem 2) + ch9 (.y of pair rem 4)
        const float nn = (ch0 == 4 ? dx * dx : 0.f) + (ch0 == 8 ? dy * dy : 0.f);
        objc += valid ? 0.5f * (1.f - wobj) * nn : 0.f;
    }

    const int nBox = 2 * nObj;

    // ---- masked pred boxes -> xyxy in LDS (global reads L1-warm from stream) ----
    for (int e = lane; e < nBox; e += 64) {
        const int c = clist[e >> 1];
        const float* pb = P + c * CH + (e & 1) * 5;
        const float cx = pb[0], cy = pb[1], bw = pb[2], bh = pb[3];
        boxS[e] = make_float4(cx - 0.5f * bw, cy - 0.5f * bh,
                              cx + 0.5f * bw, cy + 0.5f * bh);
    }

    // ---- per masked target box: max IoU over masked pred boxes; losses ----
    for (int e = lane; e < nBox; e += 64) {
        const int c = clist[e >> 1];
        const float* tb = T + c * CH + (e & 1) * 5;
        const float tcx = tb[0], tcy = tb[1], tw = tb[2], th = tb[3];
        const float tx1 = tcx - 0.5f * tw, ty1 = tcy - 0.5f * th;
        const float tx2 = tcx + 0.5f * tw, ty2 = tcy + 0.5f * th;
        const float ta = (tx2 - tx1) * (ty2 - ty1);
        float maxiou = 0.f;
        for (int i = 0; i < nBox; ++i) {
            const float4 pb4 = boxS[i];              // wave-uniform = broadcast
            const float lx = fmaxf(pb4.x, tx1), ly = fmaxf(pb4.y, ty1);
            const float rx = fminf(pb4.z, tx2), ry = fminf(pb4.w, ty2);
            const float iw = fmaxf(rx - lx, 0.f), ih = fmaxf(ry - ly, 0.f);
            const float inter = iw * ih;
            const float pa = (pb4.z - pb4.x) * (pb4.w - pb4.y);
            const float un = pa + ta - inter;
            const float iou = inter / (un > 0.f ? un : 1.f);
            maxiou = fmaxf(maxiou, iou);
        }
        if (maxiou != 0.f) {                         // cmask
            const float* pb = P + c * CH + (e & 1) * 5;
            const float dcx = pb[0] - tcx, dcy = pb[1] - tcy;
            coord += dcx * dcx + dcy * dcy;
            const float dw = sqrtf(pb[2]) - sqrtf(tw);
            const float dh = sqrtf(pb[3]) - sqrtf(th);
            coord += dw * dw + dh * dh;
            const float dc = pb[4] - tb[4];
            objc += dc * dc;
        }
    }
}

__global__ __launch_bounds__(256) void yolo_main(const float* __restrict__ pred,
                                                 const float* __restrict__ targ,
                                                 float* __restrict__ ws,
                                                 int* __restrict__ cnt,
                                                 float* __restrict__ out,
                                                 int B, float invB) {
    const int w = threadIdx.x >> 6;
    const int lane = threadIdx.x & 63;
    const int NBLK = gridDim.x;
    const int r0 = (blockIdx.x * WPB + w) * RPW;
    const int r1 = r0 + 1;
    const bool ok0 = r0 < B, ok1 = r1 < B;          // wave-uniform

    __shared__ float4 boxS[WPB][2 * CELLS];
    __shared__ int clist[WPB][CELLS];
    __shared__ float sred[WPB][3];
    __shared__ int lastFlag;

    const float* P0 = pred + (size_t)r0 * ROW;
    const float* T0 = targ + (size_t)r0 * ROW;
    const float* P1 = pred + (size_t)r1 * ROW;
    const float* T1 = targ + (size_t)r1 * ROW;

    // ---- issue BOTH rows' stream loads before any consumption ----
    float2 pv0[ITS], tv0[ITS], pv1[ITS], tv1[ITS];
    if (ok0) {
        const float2* P2 = (const float2*)P0;
        const float2* T2 = (const float2*)T0;
        #pragma unroll
        for (int it = 0; it < ITS; ++it) {
            const int j = lane + it * 64;
            const int jc = j < NPAIR ? j : NPAIR - 1;
            pv0[it] = P2[jc];
            tv0[it] = T2[jc];
        }
    }
    if (ok1) {
        const float2* P2 = (const float2*)P1;
        const float2* T2 = (const float2*)T1;
        #pragma unroll
        for (int it = 0; it < ITS; ++it) {
            const int j = lane + it * 64;
            const int jc = j < NPAIR ? j : NPAIR - 1;
            pv1[it] = P2[jc];
            tv1[it] = T2[jc];
        }
    }

    float cls = 0.f, objc = 0.f, coord = 0.f;
    if (ok0) processRow(P0, T0, pv0, tv0, lane, boxS[w], clist[w], cls, objc, coord);
    if (ok1) processRow(P1, T1, pv1, tv1, lane, boxS[w], clist[w], cls, objc, coord);

    // ---- wave reduce -> block combine -> one triple per block ----
    cls = waveReduce(cls); objc = waveReduce(objc); coord = waveReduce(coord);
    if (lane == 0) { sred[w][0] = cls; sred[w][1] = objc; sred[w][2] = coord; }
    __syncthreads();
    if (threadIdx.x == 0) {
        float c = 0.f, o = 0.f, x = 0.f;
        #pragma unroll
        for (int i = 0; i < WPB; ++i) { c += sred[i][0]; o += sred[i][1]; x += sred[i][2]; }
        ws[blockIdx.x] = c;
        ws[NBLK + blockIdx.x] = o;
        ws[2 * NBLK + blockIdx.x] = x;
        __threadfence();                              // release block triple
        const int old = atomicAdd(cnt, 1);
        lastFlag = (old == NBLK - 1) ? 1 : 0;
    }
    __syncthreads();

    // ---- last block finalizes (deterministic order) ----
    if (lastFlag) {
        __threadfence();                              // acquire other blocks' triples
        float c = 0.f, o = 0.f, x = 0.f;
        for (int i = threadIdx.x; i < NBLK; i += 256) {
            c += ws[i];
            o += ws[NBLK + i];
            x += ws[2 * NBLK + i];
        }
        c = waveReduce(c); o = waveReduce(o); x = waveReduce(x);
        if (lane == 0) { sred[w][0] = c; sred[w][1] = o; sred[w][2] = x; }
        __syncthreads();
        if (threadIdx.x == 0) {
            float C = 0.f, O = 0.f, X = 0.f;
            #pragma unroll
            for (int i = 0; i < WPB; ++i) { C += sred[i][0]; O += sred[i][1]; X += sred[i][2]; }
            const float bcls = C * invB;
            const float bobj = O * invB;               // noobj*0.5 folded upstream
            const float bcoord = X * 5.0f * invB;      // COORD_LAMBDA
            out[0] = bcls + bobj + bcoord;
            out[1] = bcls;
            out[2] = bobj;
            out[3] = bcoord;
        }
    }
}

extern "C" void kernel_launch(void* const* d_in, const int* in_sizes, int n_in,
                              void* d_out, int out_size, void* d_ws, size_t ws_size,
                              hipStream_t stream) {
    const float* pred = (const float*)d_in[0];
    const float* targ = (const float*)d_in[1];
    float* ws = (float*)d_ws;
    float* out = (float*)d_out;
    const int B = in_sizes[0] / ROW;
    const int NBLK = (B + RPW * WPB - 1) / (RPW * WPB);
    int* cnt = (int*)(ws + 3 * NBLK);

    hipMemsetAsync(cnt, 0, sizeof(int), stream);      // zero the arrival counter
    yolo_main<<<NBLK, 256, 0, stream>>>(pred, targ, ws, cnt, out, B, 1.0f / (float)B);
}